// Round 1
// baseline (1635.124 us; speedup 1.0000x reference)
//
#include <hip/hip_runtime.h>
#include <cstdint>
#include <cstddef>

#define D_MODEL 512
#define SEQ_T 2048
#define NHEADS 8
#define HDIM 64

// ---------------------------------------------------------------------------
// Kernel 1: QKV projection GEMM. x[8192,512] @ W[512,1536] + b -> Q/K/V in
// [B, H, T, Hd] layout. Tile 64x64, BK=16, 256 threads, 4x4 microtile.
// Each N-tile of 64 cols lies entirely inside one (three, head) pair.
// ---------------------------------------------------------------------------
__global__ __launch_bounds__(256) void gemm_qkv_kernel(
    const float* __restrict__ x, const float* __restrict__ W,
    const float* __restrict__ bias, float* __restrict__ Q,
    float* __restrict__ K, float* __restrict__ V) {
  __shared__ float As[16][68];   // A^T tile, pad 68 keeps float4-aligned rows
  __shared__ float Bs[16][64];
  const int t = threadIdx.x;
  const int m0 = blockIdx.x << 6;
  const int n0 = blockIdx.y << 6;
  const int tm = (t >> 4) << 2;
  const int tn = (t & 15) << 2;
  const int ar = t >> 2, ac = (t & 3) << 2;   // A tile load: row, col4
  const int bk = t >> 4, bn = (t & 15) << 2;  // B tile load: krow, ncol4
  float acc[4][4] = {};
  for (int k0 = 0; k0 < 512; k0 += 16) {
    float4 a4 = *(const float4*)(x + (size_t)(m0 + ar) * 512 + k0 + ac);
    As[ac + 0][ar] = a4.x; As[ac + 1][ar] = a4.y;
    As[ac + 2][ar] = a4.z; As[ac + 3][ar] = a4.w;
    *(float4*)(&Bs[bk][bn]) =
        *(const float4*)(W + (size_t)(k0 + bk) * 1536 + n0 + bn);
    __syncthreads();
#pragma unroll
    for (int kk = 0; kk < 16; ++kk) {
      float4 a = *(const float4*)(&As[kk][tm]);
      float4 b = *(const float4*)(&Bs[kk][tn]);
      float av[4] = {a.x, a.y, a.z, a.w};
      float bv[4] = {b.x, b.y, b.z, b.w};
#pragma unroll
      for (int i = 0; i < 4; ++i)
#pragma unroll
        for (int j = 0; j < 4; ++j) acc[i][j] = fmaf(av[i], bv[j], acc[i][j]);
    }
    __syncthreads();
  }
  const int three = n0 >> 9;          // 0:Q 1:K 2:V  (uniform per block)
  const int h = (n0 >> 6) & 7;       // head (uniform per block)
  float* dst = (three == 0) ? Q : (three == 1) ? K : V;
#pragma unroll
  for (int i = 0; i < 4; ++i) {
    int m = m0 + tm + i;
    int bb = m >> 11, tt = m & 2047;
    size_t rowbase = ((size_t)((bb << 3) + h) * SEQ_T + tt) * HDIM;
#pragma unroll
    for (int j = 0; j < 4; ++j)
      dst[rowbase + tn + j] = acc[i][j] + bias[n0 + tn + j];
  }
}

// ---------------------------------------------------------------------------
// Kernel 2: causal flash attention. Block = 256 threads = 4 waves = 4
// consecutive q rows of one (b,h). K/V staged in LDS (pad 65 -> 2-way bank
// aliasing, free). Online softmax, O accumulator 1 float/lane (lane = hd).
// ---------------------------------------------------------------------------
__global__ __launch_bounds__(256) void attn_kernel(
    const float* __restrict__ Qm, const float* __restrict__ Km,
    const float* __restrict__ Vm, float* __restrict__ AO) {
  __shared__ float Ks[64][65];
  __shared__ float Vs[64][65];
  __shared__ float ps[4][64];
  const int tid = threadIdx.x;
  const int w = tid >> 6;       // wave id = q row within block
  const int lane = tid & 63;
  const int bh = blockIdx.y;    // b*8 + h
  const int q0 = blockIdx.x << 2;
  const int qrow = q0 + w;

  // hoist scaled q row into registers (values wave-uniform)
  const float* qptr = Qm + ((size_t)bh * SEQ_T + qrow) * HDIM;
  float qreg[64];
#pragma unroll
  for (int d = 0; d < 64; ++d) qreg[d] = qptr[d] * 0.125f;  // 1/sqrt(64)

  float o = 0.f, m_i = -INFINITY, l_i = 0.f;
  const int ktiles = ((q0 + 3) >> 6) + 1;   // causal: tiles up to max q row
  const float* kbase_ptr = Km + (size_t)bh * SEQ_T * HDIM;
  const float* vbase_ptr = Vm + (size_t)bh * SEQ_T * HDIM;

  for (int kt = 0; kt < ktiles; ++kt) {
    const int kb = kt << 6;
    const float* kp = kbase_ptr + (size_t)kb * HDIM;
    const float* vp = vbase_ptr + (size_t)kb * HDIM;
    for (int i = tid; i < 64 * 64; i += 256) {
      int r = i >> 6, d = i & 63;
      Ks[r][d] = kp[i];
      Vs[r][d] = vp[i];
    }
    __syncthreads();

    // scores: lane j -> key kb+j
    float s = 0.f;
#pragma unroll
    for (int d = 0; d < 64; ++d) s = fmaf(qreg[d], Ks[lane][d], s);
    if (kb + lane > qrow) s = -INFINITY;

    // wave max
    float mx = s;
#pragma unroll
    for (int off = 32; off > 0; off >>= 1) mx = fmaxf(mx, __shfl_xor(mx, off));
    float m_new = fmaxf(m_i, mx);          // finite: key==qrow always in range
    float alpha = __expf(m_i - m_new);     // first tile: exp(-inf)=0
    float p = __expf(s - m_new);           // masked lanes -> 0
    float psum = p;
#pragma unroll
    for (int off = 32; off > 0; off >>= 1) psum += __shfl_xor(psum, off);
    l_i = l_i * alpha + psum;
    m_i = m_new;
    ps[w][lane] = p;
    __syncthreads();

    // O update: lane d accumulates sum_j p_j * V[j][d]
    float accv = 0.f;
#pragma unroll
    for (int j = 0; j < 64; ++j) accv = fmaf(ps[w][j], Vs[j][lane], accv);
    o = o * alpha + accv;
    __syncthreads();   // all waves done with Ks/Vs before re-staging
  }

  // write [B, T, H*Hd]
  const int bb = bh >> 3, h = bh & 7;
  AO[((size_t)bb * SEQ_T + qrow) * D_MODEL + (h << 6) + lane] = o * (1.0f / l_i);
}

// ---------------------------------------------------------------------------
// Kernel 3: output projection. AO[8192,512] @ W_out[512,512] + b -> out.
// ---------------------------------------------------------------------------
__global__ __launch_bounds__(256) void gemm_out_kernel(
    const float* __restrict__ A, const float* __restrict__ W,
    const float* __restrict__ bias, float* __restrict__ out) {
  __shared__ float As[16][68];
  __shared__ float Bs[16][64];
  const int t = threadIdx.x;
  const int m0 = blockIdx.x << 6;
  const int n0 = blockIdx.y << 6;
  const int tm = (t >> 4) << 2;
  const int tn = (t & 15) << 2;
  const int ar = t >> 2, ac = (t & 3) << 2;
  const int bk = t >> 4, bn = (t & 15) << 2;
  float acc[4][4] = {};
  for (int k0 = 0; k0 < 512; k0 += 16) {
    float4 a4 = *(const float4*)(A + (size_t)(m0 + ar) * 512 + k0 + ac);
    As[ac + 0][ar] = a4.x; As[ac + 1][ar] = a4.y;
    As[ac + 2][ar] = a4.z; As[ac + 3][ar] = a4.w;
    *(float4*)(&Bs[bk][bn]) =
        *(const float4*)(W + (size_t)(k0 + bk) * 512 + n0 + bn);
    __syncthreads();
#pragma unroll
    for (int kk = 0; kk < 16; ++kk) {
      float4 a = *(const float4*)(&As[kk][tm]);
      float4 b = *(const float4*)(&Bs[kk][tn]);
      float av[4] = {a.x, a.y, a.z, a.w};
      float bv[4] = {b.x, b.y, b.z, b.w};
#pragma unroll
      for (int i = 0; i < 4; ++i)
#pragma unroll
        for (int j = 0; j < 4; ++j) acc[i][j] = fmaf(av[i], bv[j], acc[i][j]);
    }
    __syncthreads();
  }
#pragma unroll
  for (int i = 0; i < 4; ++i) {
    int m = m0 + tm + i;
#pragma unroll
    for (int j = 0; j < 4; ++j)
      out[(size_t)m * 512 + n0 + tn + j] = acc[i][j] + bias[n0 + tn + j];
  }
}

// ---------------------------------------------------------------------------
extern "C" void kernel_launch(void* const* d_in, const int* in_sizes, int n_in,
                              void* d_out, int out_size, void* d_ws,
                              size_t ws_size, hipStream_t stream) {
  const float* x     = (const float*)d_in[0];
  const float* W_qkv = (const float*)d_in[1];
  const float* b_qkv = (const float*)d_in[2];
  const float* W_out = (const float*)d_in[3];
  const float* b_out = (const float*)d_in[4];
  float* out = (float*)d_out;

  const size_t SZ = (size_t)4 * NHEADS * SEQ_T * HDIM;  // 4,194,304 floats
  float* Q  = (float*)d_ws;
  float* K  = Q + SZ;
  float* V  = K + SZ;
  float* AO = V + SZ;

  // QKV projection: M=8192 (128 tiles), N=1536 (24 tiles)
  gemm_qkv_kernel<<<dim3(128, 24), 256, 0, stream>>>(x, W_qkv, b_qkv, Q, K, V);
  // attention: 4 q-rows per block, one (b,h) per blockIdx.y
  attn_kernel<<<dim3(SEQ_T / 4, 4 * NHEADS), 256, 0, stream>>>(Q, K, V, AO);
  // output projection: M=8192, N=512 (8 tiles)
  gemm_out_kernel<<<dim3(128, 8), 256, 0, stream>>>(AO, W_out, b_out, out);
}

// Round 2
// 437.472 us; speedup vs baseline: 3.7377x; 3.7377x over previous
//
#include <hip/hip_runtime.h>
#include <cstdint>
#include <cstddef>

#define D_MODEL 512
#define SEQ_T 2048
#define NHEADS 8
#define HDIM 64

typedef __attribute__((ext_vector_type(8))) short bf16x8;
typedef __attribute__((ext_vector_type(4))) float f32x4;

__device__ __forceinline__ unsigned short f2bf(float f) {
  unsigned int u = __float_as_uint(f);
  u += 0x7FFFu + ((u >> 16) & 1u);
  return (unsigned short)(u >> 16);
}

// Q pre-scaled by 1/sqrt(64) * log2(e) so softmax runs in exp2 domain.
#define QSCALE 0.18033688011112043f

// ---------------------------------------------------------------------------
// Kernel 1: QKV projection GEMM (fp32 compute). x[8192,512] @ W[512,1536] + b.
// Epilogue: Q,K -> bf16 [bh][t][64] (Q pre-scaled); V -> bf16 transposed
// [bh][dv][t] so attention's PV B-fragments read contiguous LDS.
// ---------------------------------------------------------------------------
__global__ __launch_bounds__(256) void gemm_qkv_kernel(
    const float* __restrict__ x, const float* __restrict__ W,
    const float* __restrict__ bias, unsigned short* __restrict__ Qb,
    unsigned short* __restrict__ Kb, unsigned short* __restrict__ Vtb) {
  __shared__ float As[16][68];
  __shared__ float Bs[16][64];
  const int t = threadIdx.x;
  const int m0 = blockIdx.x << 6;
  const int n0 = blockIdx.y << 6;
  const int tm = (t >> 4) << 2;
  const int tn = (t & 15) << 2;
  const int ar = t >> 2, ac = (t & 3) << 2;
  const int bk = t >> 4, bn = (t & 15) << 2;
  float acc[4][4] = {};
  for (int k0 = 0; k0 < 512; k0 += 16) {
    float4 a4 = *(const float4*)(x + (size_t)(m0 + ar) * 512 + k0 + ac);
    As[ac + 0][ar] = a4.x; As[ac + 1][ar] = a4.y;
    As[ac + 2][ar] = a4.z; As[ac + 3][ar] = a4.w;
    *(float4*)(&Bs[bk][bn]) =
        *(const float4*)(W + (size_t)(k0 + bk) * 1536 + n0 + bn);
    __syncthreads();
#pragma unroll
    for (int kk = 0; kk < 16; ++kk) {
      float4 a = *(const float4*)(&As[kk][tm]);
      float4 b = *(const float4*)(&Bs[kk][tn]);
      float av[4] = {a.x, a.y, a.z, a.w};
      float bv[4] = {b.x, b.y, b.z, b.w};
#pragma unroll
      for (int i = 0; i < 4; ++i)
#pragma unroll
        for (int j = 0; j < 4; ++j) acc[i][j] = fmaf(av[i], bv[j], acc[i][j]);
    }
    __syncthreads();
  }
  const int three = n0 >> 9;      // 0:Q 1:K 2:V (uniform per block)
  const int h = (n0 >> 6) & 7;
  const int m = m0 + tm;
  const int bb = m >> 11, tt = m & 2047;
  const int bh = (bb << 3) + h;
  if (three == 2) {
    // V: write transposed [bh][dv][t], 4 bf16 (consecutive t) per store
#pragma unroll
    for (int j = 0; j < 4; ++j) {
      float b = bias[n0 + tn + j];
      ushort4 v4 = {f2bf(acc[0][j] + b), f2bf(acc[1][j] + b),
                    f2bf(acc[2][j] + b), f2bf(acc[3][j] + b)};
      *(ushort4*)(Vtb + ((size_t)bh * HDIM + tn + j) * SEQ_T + tt) = v4;
    }
  } else {
    unsigned short* dst = (three == 0) ? Qb : Kb;
    const float sc = (three == 0) ? QSCALE : 1.0f;
#pragma unroll
    for (int i = 0; i < 4; ++i) {
      ushort4 v4 = {f2bf((acc[i][0] + bias[n0 + tn + 0]) * sc),
                    f2bf((acc[i][1] + bias[n0 + tn + 1]) * sc),
                    f2bf((acc[i][2] + bias[n0 + tn + 2]) * sc),
                    f2bf((acc[i][3] + bias[n0 + tn + 3]) * sc)};
      *(ushort4*)(dst + ((size_t)bh * SEQ_T + tt + i) * HDIM + tn) = v4;
    }
  }
}

// ---------------------------------------------------------------------------
// Kernel 2: causal flash attention, bf16 MFMA (16x16x32).
// Block = 256 thr = 4 waves; 64 q-rows/block (16/wave). K-tile = 64 keys.
// Ks [key][d], Vs [dv][key] (transposed), stride 72 ushorts (bank-safe).
// Online softmax in C-fragment registers (row = quad*4+reg), shfl_xor
// reductions over lane bits 0-3. P C->A layout via wave-private LDS.
// ---------------------------------------------------------------------------
__global__ __launch_bounds__(256) void attn_mfma_kernel(
    const unsigned short* __restrict__ Qb, const unsigned short* __restrict__ Kb,
    const unsigned short* __restrict__ Vtb, float* __restrict__ AO) {
  __shared__ __align__(16) unsigned short Ks[64][72];
  __shared__ __align__(16) unsigned short Vs[64][72];
  __shared__ __align__(16) unsigned short Ps[4][16][72];
  const int tid = threadIdx.x;
  const int w = tid >> 6, lane = tid & 63;
  const int quad = lane >> 4, l15 = lane & 15;
  const int bh = blockIdx.y;
  const int q0 = (int)(gridDim.x - 1 - blockIdx.x) << 6;  // longest first
  const int rowbase = q0 + w * 16;

  // Q A-fragments, loaded once from global (A[m=l15][k=quad*8+j], ks=0/1)
  bf16x8 qf0, qf1;
  {
    const unsigned short* qp =
        Qb + ((size_t)bh * SEQ_T + rowbase + l15) * HDIM + quad * 8;
    qf0 = *(const bf16x8*)(qp);
    qf1 = *(const bf16x8*)(qp + 32);
  }
  f32x4 O[4] = {{0.f, 0.f, 0.f, 0.f}, {0.f, 0.f, 0.f, 0.f},
                {0.f, 0.f, 0.f, 0.f}, {0.f, 0.f, 0.f, 0.f}};
  float m_i[4] = {-INFINITY, -INFINITY, -INFINITY, -INFINITY};
  float l_i[4] = {0.f, 0.f, 0.f, 0.f};

  const unsigned short* kbase = Kb + (size_t)bh * SEQ_T * HDIM;
  const unsigned short* vbase = Vtb + (size_t)bh * HDIM * SEQ_T;
  const int ktiles = (q0 >> 6) + 1;
  const int sr = tid >> 3, sc = (tid & 7) * 8;  // staging row/col

  for (int kt = 0; kt < ktiles; ++kt) {
    const int kb = kt << 6;
    // stage K tile [64][64] and Vt tile [64 dv][64 key]
    *(uint4*)&Ks[sr][sc] = *(const uint4*)(kbase + (size_t)(kb + sr) * 64 + sc);
    *(uint4*)&Ks[sr + 32][sc] =
        *(const uint4*)(kbase + (size_t)(kb + sr + 32) * 64 + sc);
    *(uint4*)&Vs[sr][sc] = *(const uint4*)(vbase + (size_t)sr * SEQ_T + kb + sc);
    *(uint4*)&Vs[sr + 32][sc] =
        *(const uint4*)(vbase + (size_t)(sr + 32) * SEQ_T + kb + sc);
    __syncthreads();

    // S = Q @ K^T  (4 n-blocks of 16 keys)
    f32x4 S[4] = {{0.f, 0.f, 0.f, 0.f}, {0.f, 0.f, 0.f, 0.f},
                  {0.f, 0.f, 0.f, 0.f}, {0.f, 0.f, 0.f, 0.f}};
#pragma unroll
    for (int nb = 0; nb < 4; ++nb) {
      const unsigned short* kr = &Ks[nb * 16 + l15][quad * 8];
      S[nb] = __builtin_amdgcn_mfma_f32_16x16x32_bf16(
          qf0, *(const bf16x8*)(kr), S[nb], 0, 0, 0);
      S[nb] = __builtin_amdgcn_mfma_f32_16x16x32_bf16(
          qf1, *(const bf16x8*)(kr + 32), S[nb], 0, 0, 0);
    }

    // causal mask (only the diagonal tile can clip)
    if (kt == ktiles - 1) {
#pragma unroll
      for (int nb = 0; nb < 4; ++nb)
#pragma unroll
        for (int r = 0; r < 4; ++r) {
          int col = kb + nb * 16 + l15;
          int row = rowbase + quad * 4 + r;
          if (col > row) S[nb][r] = -INFINITY;
        }
    }

    // online softmax (exp2 domain; Q pre-scaled by 0.125*log2e)
    float alpha[4];
#pragma unroll
    for (int r = 0; r < 4; ++r) {
      float mx = fmaxf(fmaxf(S[0][r], S[1][r]), fmaxf(S[2][r], S[3][r]));
#pragma unroll
      for (int off = 1; off <= 8; off <<= 1)
        mx = fmaxf(mx, __shfl_xor(mx, off));
      float mnew = fmaxf(m_i[r], mx);
      alpha[r] = exp2f(m_i[r] - mnew);
      m_i[r] = mnew;
    }
    float rs[4] = {0.f, 0.f, 0.f, 0.f};
#pragma unroll
    for (int nb = 0; nb < 4; ++nb)
#pragma unroll
      for (int r = 0; r < 4; ++r) {
        float p = exp2f(S[nb][r] - m_i[r]);
        S[nb][r] = p;
        rs[r] += p;
      }
#pragma unroll
    for (int r = 0; r < 4; ++r) {
#pragma unroll
      for (int off = 1; off <= 8; off <<= 1) rs[r] += __shfl_xor(rs[r], off);
      l_i[r] = l_i[r] * alpha[r] + rs[r];
    }
#pragma unroll
    for (int nb = 0; nb < 4; ++nb)
#pragma unroll
      for (int r = 0; r < 4; ++r) O[nb][r] *= alpha[r];

    // P: C-layout regs -> wave-private LDS -> A-layout fragments
#pragma unroll
    for (int nb = 0; nb < 4; ++nb)
#pragma unroll
      for (int r = 0; r < 4; ++r)
        Ps[w][quad * 4 + r][nb * 16 + l15] = f2bf(S[nb][r]);
    bf16x8 pf0 = *(const bf16x8*)&Ps[w][l15][quad * 8];
    bf16x8 pf1 = *(const bf16x8*)&Ps[w][l15][quad * 8 + 32];

    // O += P @ V   (B-frag: V[k=key][n=dv] = Vs[dv][key], contiguous key)
#pragma unroll
    for (int nb = 0; nb < 4; ++nb) {
      const unsigned short* vr = &Vs[nb * 16 + l15][quad * 8];
      O[nb] = __builtin_amdgcn_mfma_f32_16x16x32_bf16(
          pf0, *(const bf16x8*)(vr), O[nb], 0, 0, 0);
      O[nb] = __builtin_amdgcn_mfma_f32_16x16x32_bf16(
          pf1, *(const bf16x8*)(vr + 32), O[nb], 0, 0, 0);
    }
    __syncthreads();
  }

  // epilogue: AO[b][t][h*64+dv] fp32
  const int bb = bh >> 3, h = bh & 7;
#pragma unroll
  for (int r = 0; r < 4; ++r) {
    float inv = 1.0f / l_i[r];
    int row = rowbase + quad * 4 + r;
    float* dst = AO + ((size_t)bb * SEQ_T + row) * D_MODEL + (h << 6);
#pragma unroll
    for (int nb = 0; nb < 4; ++nb) dst[nb * 16 + l15] = O[nb][r] * inv;
  }
}

// ---------------------------------------------------------------------------
// Kernel 3: output projection (fp32). AO[8192,512] @ W_out[512,512] + b.
// ---------------------------------------------------------------------------
__global__ __launch_bounds__(256) void gemm_out_kernel(
    const float* __restrict__ A, const float* __restrict__ W,
    const float* __restrict__ bias, float* __restrict__ out) {
  __shared__ float As[16][68];
  __shared__ float Bs[16][64];
  const int t = threadIdx.x;
  const int m0 = blockIdx.x << 6;
  const int n0 = blockIdx.y << 6;
  const int tm = (t >> 4) << 2;
  const int tn = (t & 15) << 2;
  const int ar = t >> 2, ac = (t & 3) << 2;
  const int bk = t >> 4, bn = (t & 15) << 2;
  float acc[4][4] = {};
  for (int k0 = 0; k0 < 512; k0 += 16) {
    float4 a4 = *(const float4*)(A + (size_t)(m0 + ar) * 512 + k0 + ac);
    As[ac + 0][ar] = a4.x; As[ac + 1][ar] = a4.y;
    As[ac + 2][ar] = a4.z; As[ac + 3][ar] = a4.w;
    *(float4*)(&Bs[bk][bn]) =
        *(const float4*)(W + (size_t)(k0 + bk) * 512 + n0 + bn);
    __syncthreads();
#pragma unroll
    for (int kk = 0; kk < 16; ++kk) {
      float4 a = *(const float4*)(&As[kk][tm]);
      float4 b = *(const float4*)(&Bs[kk][tn]);
      float av[4] = {a.x, a.y, a.z, a.w};
      float bv[4] = {b.x, b.y, b.z, b.w};
#pragma unroll
      for (int i = 0; i < 4; ++i)
#pragma unroll
        for (int j = 0; j < 4; ++j) acc[i][j] = fmaf(av[i], bv[j], acc[i][j]);
    }
    __syncthreads();
  }
#pragma unroll
  for (int i = 0; i < 4; ++i) {
    int m = m0 + tm + i;
#pragma unroll
    for (int j = 0; j < 4; ++j)
      out[(size_t)m * 512 + n0 + tn + j] = acc[i][j] + bias[n0 + tn + j];
  }
}

// ---------------------------------------------------------------------------
extern "C" void kernel_launch(void* const* d_in, const int* in_sizes, int n_in,
                              void* d_out, int out_size, void* d_ws,
                              size_t ws_size, hipStream_t stream) {
  const float* x     = (const float*)d_in[0];
  const float* W_qkv = (const float*)d_in[1];
  const float* b_qkv = (const float*)d_in[2];
  const float* W_out = (const float*)d_in[3];
  const float* b_out = (const float*)d_in[4];
  float* out = (float*)d_out;

  const size_t SZ = (size_t)4 * NHEADS * SEQ_T * HDIM;  // 4,194,304 elems
  unsigned short* Qb  = (unsigned short*)d_ws;
  unsigned short* Kb  = Qb + SZ;
  unsigned short* Vtb = Kb + SZ;
  float* AO = (float*)(Vtb + SZ);

  gemm_qkv_kernel<<<dim3(128, 24), 256, 0, stream>>>(x, W_qkv, b_qkv, Qb, Kb,
                                                     Vtb);
  attn_mfma_kernel<<<dim3(SEQ_T / 64, 4 * NHEADS), 256, 0, stream>>>(Qb, Kb,
                                                                     Vtb, AO);
  gemm_out_kernel<<<dim3(128, 8), 256, 0, stream>>>(AO, W_out, b_out, out);
}

// Round 3
// 250.402 us; speedup vs baseline: 6.5300x; 1.7471x over previous
//
#include <hip/hip_runtime.h>
#include <cstdint>
#include <cstddef>

#define D_MODEL 512
#define SEQ_T 2048
#define NHEADS 8
#define HDIM 64

typedef __attribute__((ext_vector_type(8))) short bf16x8;
typedef __attribute__((ext_vector_type(4))) float f32x4;

__device__ __forceinline__ unsigned short f2bf(float f) {
  unsigned int u = __float_as_uint(f);
  u += 0x7FFFu + ((u >> 16) & 1u);
  return (unsigned short)(u >> 16);
}

// Q pre-scaled by 1/sqrt(64) * log2(e) so softmax runs in exp2 domain.
#define QSCALE 0.18033688011112043f

// async global->LDS, 16B per lane. LDS dest = wave-uniform base + lane*16.
__device__ __forceinline__ void async_lds16(const unsigned short* g,
                                            unsigned short* l) {
  __builtin_amdgcn_global_load_lds(
      (const __attribute__((address_space(1))) void*)g,
      (__attribute__((address_space(3))) void*)l, 16, 0, 0);
}

// ---------------------------------------------------------------------------
// Prep 0: elementwise fp32 -> bf16 (n multiple of 2048)
// ---------------------------------------------------------------------------
__global__ __launch_bounds__(256) void cast_bf16_kernel(
    const float* __restrict__ in, unsigned short* __restrict__ outp) {
  int i = (blockIdx.x * 256 + threadIdx.x) * 8;
  float4 a = *(const float4*)(in + i);
  float4 b = *(const float4*)(in + i + 4);
  ushort4 lo = {f2bf(a.x), f2bf(a.y), f2bf(a.z), f2bf(a.w)};
  ushort4 hi = {f2bf(b.x), f2bf(b.y), f2bf(b.z), f2bf(b.w)};
  *(ushort4*)(outp + i) = lo;
  *(ushort4*)(outp + i + 4) = hi;
}

// ---------------------------------------------------------------------------
// Prep 1: cast + transpose. in [R][C] fp32 -> out [C][R] bf16. 64x64 tiles.
// ---------------------------------------------------------------------------
__global__ __launch_bounds__(256) void transpose_cast_kernel(
    const float* __restrict__ in, unsigned short* __restrict__ outp, int R,
    int C) {
  __shared__ float tile[64][65];
  const int c0 = blockIdx.x * 64, r0 = blockIdx.y * 64;
  for (int i = threadIdx.x; i < 64 * 64; i += 256) {
    int r = i >> 6, c = i & 63;
    tile[r][c] = in[(size_t)(r0 + r) * C + c0 + c];
  }
  __syncthreads();
  for (int i = threadIdx.x; i < 64 * 64; i += 256) {
    int c = i >> 6, r = i & 63;
    outp[(size_t)(c0 + c) * R + r0 + r] = f2bf(tile[r][c]);
  }
}

// ---------------------------------------------------------------------------
// Kernel 1: QKV projection, bf16 MFMA. xb[8192][512] @ Wt[1536][512]^T + b.
// m97 structure: 128x128 tile, BK=32, 4 waves (2x2), 4x4 16x16x32 MFMA each.
// Epilogue: Q,K bf16 [bh][t][64] (Q pre-scaled by QSCALE); V bf16 transposed
// [bh][dv][t] via ushort4 (regs r=0..3 are consecutive t).
// ---------------------------------------------------------------------------
__global__ __launch_bounds__(256) void gemm_qkv_mfma(
    const unsigned short* __restrict__ xb, const unsigned short* __restrict__ Wt,
    const float* __restrict__ bias, unsigned short* __restrict__ Qb,
    unsigned short* __restrict__ Kb, unsigned short* __restrict__ Vtb) {
  __shared__ unsigned short As[128 * 32];  // [row][k], row stride 32 elems
  __shared__ unsigned short Bs[128 * 32];
  const int tid = threadIdx.x;
  const int w = tid >> 6, lane = tid & 63;
  const int quad = lane >> 4, l15 = lane & 15;
  const int wm = w >> 1, wn = w & 1;
  const int m0 = blockIdx.x * 128, n0 = blockIdx.y * 128;

  const unsigned short* ga = xb + (size_t)(m0 + (tid >> 2)) * 512 + (tid & 3) * 8;
  const unsigned short* gb = Wt + (size_t)(n0 + (tid >> 2)) * 512 + (tid & 3) * 8;
  unsigned short* lA = As + tid * 8;
  unsigned short* lB = Bs + tid * 8;

  f32x4 acc[4][4] = {};
  for (int k0 = 0; k0 < 512; k0 += 32) {
    async_lds16(ga + k0, lA);
    async_lds16(ga + 64 * 512 + k0, lA + 2048);
    async_lds16(gb + k0, lB);
    async_lds16(gb + 64 * 512 + k0, lB + 2048);
    __syncthreads();
    bf16x8 af[4], bfr[4];
#pragma unroll
    for (int mb = 0; mb < 4; ++mb)
      af[mb] = *(const bf16x8*)&As[(wm * 64 + mb * 16 + l15) * 32 + quad * 8];
#pragma unroll
    for (int nb = 0; nb < 4; ++nb)
      bfr[nb] = *(const bf16x8*)&Bs[(wn * 64 + nb * 16 + l15) * 32 + quad * 8];
#pragma unroll
    for (int mb = 0; mb < 4; ++mb)
#pragma unroll
      for (int nb = 0; nb < 4; ++nb)
        acc[mb][nb] = __builtin_amdgcn_mfma_f32_16x16x32_bf16(
            af[mb], bfr[nb], acc[mb][nb], 0, 0, 0);
    __syncthreads();
  }

  const int cbase = n0 + wn * 64;          // wave-uniform, 64-aligned
  const int three = cbase >> 9;            // 0:Q 1:K 2:V
  const int h = (cbase >> 6) & 7;
  const int bh = ((m0 >> 11) << 3) + h;
  const int t0 = (m0 & 2047) + wm * 64;
  float bv[4];
#pragma unroll
  for (int nb = 0; nb < 4; ++nb) bv[nb] = bias[cbase + nb * 16 + l15];

  if (three == 2) {
#pragma unroll
    for (int mb = 0; mb < 4; ++mb)
#pragma unroll
      for (int nb = 0; nb < 4; ++nb) {
        int trow = t0 + mb * 16 + quad * 4;
        ushort4 v = {f2bf(acc[mb][nb][0] + bv[nb]), f2bf(acc[mb][nb][1] + bv[nb]),
                     f2bf(acc[mb][nb][2] + bv[nb]), f2bf(acc[mb][nb][3] + bv[nb])};
        *(ushort4*)(Vtb + ((size_t)bh * HDIM + nb * 16 + l15) * SEQ_T + trow) = v;
      }
  } else {
    unsigned short* dst = three ? Kb : Qb;
    const float sc = three ? 1.0f : QSCALE;
#pragma unroll
    for (int mb = 0; mb < 4; ++mb)
#pragma unroll
      for (int nb = 0; nb < 4; ++nb)
#pragma unroll
        for (int r = 0; r < 4; ++r) {
          int trow = t0 + mb * 16 + quad * 4 + r;
          dst[((size_t)bh * SEQ_T + trow) * HDIM + nb * 16 + l15] =
              f2bf((acc[mb][nb][r] + bv[nb]) * sc);
        }
  }
}

// ---------------------------------------------------------------------------
// Kernel 2: causal flash attention, bf16 MFMA (unchanged from r2 except
// bf16 AO output). Block = 4 waves, 64 q-rows; K-tile = 64 keys.
// ---------------------------------------------------------------------------
__global__ __launch_bounds__(256) void attn_mfma_kernel(
    const unsigned short* __restrict__ Qb, const unsigned short* __restrict__ Kb,
    const unsigned short* __restrict__ Vtb, unsigned short* __restrict__ AOb) {
  __shared__ __align__(16) unsigned short Ks[64][72];
  __shared__ __align__(16) unsigned short Vs[64][72];
  __shared__ __align__(16) unsigned short Ps[4][16][72];
  const int tid = threadIdx.x;
  const int w = tid >> 6, lane = tid & 63;
  const int quad = lane >> 4, l15 = lane & 15;
  const int bh = blockIdx.y;
  const int q0 = (int)(gridDim.x - 1 - blockIdx.x) << 6;  // longest first
  const int rowbase = q0 + w * 16;

  bf16x8 qf0, qf1;
  {
    const unsigned short* qp =
        Qb + ((size_t)bh * SEQ_T + rowbase + l15) * HDIM + quad * 8;
    qf0 = *(const bf16x8*)(qp);
    qf1 = *(const bf16x8*)(qp + 32);
  }
  f32x4 O[4] = {{0.f, 0.f, 0.f, 0.f}, {0.f, 0.f, 0.f, 0.f},
                {0.f, 0.f, 0.f, 0.f}, {0.f, 0.f, 0.f, 0.f}};
  float m_i[4] = {-INFINITY, -INFINITY, -INFINITY, -INFINITY};
  float l_i[4] = {0.f, 0.f, 0.f, 0.f};

  const unsigned short* kbase = Kb + (size_t)bh * SEQ_T * HDIM;
  const unsigned short* vbase = Vtb + (size_t)bh * HDIM * SEQ_T;
  const int ktiles = (q0 >> 6) + 1;
  const int sr = tid >> 3, sc = (tid & 7) * 8;

  for (int kt = 0; kt < ktiles; ++kt) {
    const int kb = kt << 6;
    *(uint4*)&Ks[sr][sc] = *(const uint4*)(kbase + (size_t)(kb + sr) * 64 + sc);
    *(uint4*)&Ks[sr + 32][sc] =
        *(const uint4*)(kbase + (size_t)(kb + sr + 32) * 64 + sc);
    *(uint4*)&Vs[sr][sc] = *(const uint4*)(vbase + (size_t)sr * SEQ_T + kb + sc);
    *(uint4*)&Vs[sr + 32][sc] =
        *(const uint4*)(vbase + (size_t)(sr + 32) * SEQ_T + kb + sc);
    __syncthreads();

    f32x4 S[4] = {{0.f, 0.f, 0.f, 0.f}, {0.f, 0.f, 0.f, 0.f},
                  {0.f, 0.f, 0.f, 0.f}, {0.f, 0.f, 0.f, 0.f}};
#pragma unroll
    for (int nb = 0; nb < 4; ++nb) {
      const unsigned short* kr = &Ks[nb * 16 + l15][quad * 8];
      S[nb] = __builtin_amdgcn_mfma_f32_16x16x32_bf16(
          qf0, *(const bf16x8*)(kr), S[nb], 0, 0, 0);
      S[nb] = __builtin_amdgcn_mfma_f32_16x16x32_bf16(
          qf1, *(const bf16x8*)(kr + 32), S[nb], 0, 0, 0);
    }

    if (kt == ktiles - 1) {
#pragma unroll
      for (int nb = 0; nb < 4; ++nb)
#pragma unroll
        for (int r = 0; r < 4; ++r) {
          int col = kb + nb * 16 + l15;
          int row = rowbase + quad * 4 + r;
          if (col > row) S[nb][r] = -INFINITY;
        }
    }

    float alpha[4];
#pragma unroll
    for (int r = 0; r < 4; ++r) {
      float mx = fmaxf(fmaxf(S[0][r], S[1][r]), fmaxf(S[2][r], S[3][r]));
#pragma unroll
      for (int off = 1; off <= 8; off <<= 1)
        mx = fmaxf(mx, __shfl_xor(mx, off));
      float mnew = fmaxf(m_i[r], mx);
      alpha[r] = exp2f(m_i[r] - mnew);
      m_i[r] = mnew;
    }
    float rs[4] = {0.f, 0.f, 0.f, 0.f};
#pragma unroll
    for (int nb = 0; nb < 4; ++nb)
#pragma unroll
      for (int r = 0; r < 4; ++r) {
        float p = exp2f(S[nb][r] - m_i[r]);
        S[nb][r] = p;
        rs[r] += p;
      }
#pragma unroll
    for (int r = 0; r < 4; ++r) {
#pragma unroll
      for (int off = 1; off <= 8; off <<= 1) rs[r] += __shfl_xor(rs[r], off);
      l_i[r] = l_i[r] * alpha[r] + rs[r];
    }
#pragma unroll
    for (int nb = 0; nb < 4; ++nb)
#pragma unroll
      for (int r = 0; r < 4; ++r) O[nb][r] *= alpha[r];

#pragma unroll
    for (int nb = 0; nb < 4; ++nb)
#pragma unroll
      for (int r = 0; r < 4; ++r)
        Ps[w][quad * 4 + r][nb * 16 + l15] = f2bf(S[nb][r]);
    bf16x8 pf0 = *(const bf16x8*)&Ps[w][l15][quad * 8];
    bf16x8 pf1 = *(const bf16x8*)&Ps[w][l15][quad * 8 + 32];

#pragma unroll
    for (int nb = 0; nb < 4; ++nb) {
      const unsigned short* vr = &Vs[nb * 16 + l15][quad * 8];
      O[nb] = __builtin_amdgcn_mfma_f32_16x16x32_bf16(
          pf0, *(const bf16x8*)(vr), O[nb], 0, 0, 0);
      O[nb] = __builtin_amdgcn_mfma_f32_16x16x32_bf16(
          pf1, *(const bf16x8*)(vr + 32), O[nb], 0, 0, 0);
    }
    __syncthreads();
  }

  const int bb = bh >> 3, h = bh & 7;
#pragma unroll
  for (int r = 0; r < 4; ++r) {
    float inv = 1.0f / l_i[r];
    int row = rowbase + quad * 4 + r;
    unsigned short* dst = AOb + ((size_t)bb * SEQ_T + row) * D_MODEL + (h << 6);
#pragma unroll
    for (int nb = 0; nb < 4; ++nb) dst[nb * 16 + l15] = f2bf(O[nb][r] * inv);
  }
}

// ---------------------------------------------------------------------------
// Kernel 3: output projection, bf16 MFMA. AOb[8192][512] @ Wot[512][512]^T
// + b -> fp32 out. Same m97 structure.
// ---------------------------------------------------------------------------
__global__ __launch_bounds__(256) void gemm_out_mfma(
    const unsigned short* __restrict__ AOb, const unsigned short* __restrict__ Wot,
    const float* __restrict__ bias, float* __restrict__ out) {
  __shared__ unsigned short As[128 * 32];
  __shared__ unsigned short Bs[128 * 32];
  const int tid = threadIdx.x;
  const int w = tid >> 6, lane = tid & 63;
  const int quad = lane >> 4, l15 = lane & 15;
  const int wm = w >> 1, wn = w & 1;
  const int m0 = blockIdx.x * 128, n0 = blockIdx.y * 128;

  const unsigned short* ga = AOb + (size_t)(m0 + (tid >> 2)) * 512 + (tid & 3) * 8;
  const unsigned short* gb = Wot + (size_t)(n0 + (tid >> 2)) * 512 + (tid & 3) * 8;
  unsigned short* lA = As + tid * 8;
  unsigned short* lB = Bs + tid * 8;

  f32x4 acc[4][4] = {};
  for (int k0 = 0; k0 < 512; k0 += 32) {
    async_lds16(ga + k0, lA);
    async_lds16(ga + 64 * 512 + k0, lA + 2048);
    async_lds16(gb + k0, lB);
    async_lds16(gb + 64 * 512 + k0, lB + 2048);
    __syncthreads();
    bf16x8 af[4], bfr[4];
#pragma unroll
    for (int mb = 0; mb < 4; ++mb)
      af[mb] = *(const bf16x8*)&As[(wm * 64 + mb * 16 + l15) * 32 + quad * 8];
#pragma unroll
    for (int nb = 0; nb < 4; ++nb)
      bfr[nb] = *(const bf16x8*)&Bs[(wn * 64 + nb * 16 + l15) * 32 + quad * 8];
#pragma unroll
    for (int mb = 0; mb < 4; ++mb)
#pragma unroll
      for (int nb = 0; nb < 4; ++nb)
        acc[mb][nb] = __builtin_amdgcn_mfma_f32_16x16x32_bf16(
            af[mb], bfr[nb], acc[mb][nb], 0, 0, 0);
    __syncthreads();
  }

  const int cbase = n0 + wn * 64;
  const int rbase = m0 + wm * 64;
  float bv[4];
#pragma unroll
  for (int nb = 0; nb < 4; ++nb) bv[nb] = bias[cbase + nb * 16 + l15];
#pragma unroll
  for (int mb = 0; mb < 4; ++mb)
#pragma unroll
    for (int nb = 0; nb < 4; ++nb)
#pragma unroll
      for (int r = 0; r < 4; ++r)
        out[(size_t)(rbase + mb * 16 + quad * 4 + r) * 512 + cbase + nb * 16 +
            l15] = acc[mb][nb][r] + bv[nb];
}

// ---------------------------------------------------------------------------
extern "C" void kernel_launch(void* const* d_in, const int* in_sizes, int n_in,
                              void* d_out, int out_size, void* d_ws,
                              size_t ws_size, hipStream_t stream) {
  const float* x     = (const float*)d_in[0];
  const float* W_qkv = (const float*)d_in[1];
  const float* b_qkv = (const float*)d_in[2];
  const float* W_out = (const float*)d_in[3];
  const float* b_out = (const float*)d_in[4];
  float* out = (float*)d_out;

  const size_t NX = (size_t)4 * SEQ_T * D_MODEL;        // 4,194,304
  unsigned short* xb   = (unsigned short*)d_ws;          // [8192][512]
  unsigned short* Wqkt = xb + NX;                        // [1536][512]
  unsigned short* Wot  = Wqkt + (size_t)1536 * 512;      // [512][512]
  unsigned short* Qb   = Wot + (size_t)512 * 512;        // [bh][t][64]
  unsigned short* Kb   = Qb + NX;
  unsigned short* Vtb  = Kb + NX;                        // [bh][dv][t]
  unsigned short* AOb  = Vtb + NX;                       // [8192][512]

  cast_bf16_kernel<<<NX / 2048, 256, 0, stream>>>(x, xb);
  transpose_cast_kernel<<<dim3(24, 8), 256, 0, stream>>>(W_qkv, Wqkt, 512, 1536);
  transpose_cast_kernel<<<dim3(8, 8), 256, 0, stream>>>(W_out, Wot, 512, 512);

  gemm_qkv_mfma<<<dim3(64, 12), 256, 0, stream>>>(xb, Wqkt, b_qkv, Qb, Kb, Vtb);
  attn_mfma_kernel<<<dim3(SEQ_T / 64, 4 * NHEADS), 256, 0, stream>>>(Qb, Kb,
                                                                     Vtb, AOb);
  gemm_out_mfma<<<dim3(64, 4), 256, 0, stream>>>(AOb, Wot, b_out, out);
}

// Round 4
// 179.895 us; speedup vs baseline: 9.0893x; 1.3919x over previous
//
#include <hip/hip_runtime.h>
#include <cstdint>
#include <cstddef>

#define D_MODEL 512
#define SEQ_T 2048
#define NHEADS 8
#define HDIM 64

typedef __attribute__((ext_vector_type(8))) short bf16x8;
typedef __attribute__((ext_vector_type(4))) float f32x4;

__device__ __forceinline__ unsigned short f2bf(float f) {
  unsigned int u = __float_as_uint(f);
  u += 0x7FFFu + ((u >> 16) & 1u);
  return (unsigned short)(u >> 16);
}

// Q pre-scaled by 1/sqrt(64) * log2(e) so softmax runs in exp2 domain.
#define QSCALE 0.18033688011112043f

// async global->LDS, 16B per lane. LDS dest = wave-uniform base + lane*16.
__device__ __forceinline__ void async_lds16(const unsigned short* g,
                                            unsigned short* l) {
  __builtin_amdgcn_global_load_lds(
      (const __attribute__((address_space(1))) void*)g,
      (__attribute__((address_space(3))) void*)l, 16, 0, 0);
}

// ---------------------------------------------------------------------------
// Prep 0: elementwise fp32 -> bf16 (n multiple of 2048)
// ---------------------------------------------------------------------------
__global__ __launch_bounds__(256) void cast_bf16_kernel(
    const float* __restrict__ in, unsigned short* __restrict__ outp) {
  int i = (blockIdx.x * 256 + threadIdx.x) * 8;
  float4 a = *(const float4*)(in + i);
  float4 b = *(const float4*)(in + i + 4);
  ushort4 lo = {f2bf(a.x), f2bf(a.y), f2bf(a.z), f2bf(a.w)};
  ushort4 hi = {f2bf(b.x), f2bf(b.y), f2bf(b.z), f2bf(b.w)};
  *(ushort4*)(outp + i) = lo;
  *(ushort4*)(outp + i + 4) = hi;
}

// ---------------------------------------------------------------------------
// Prep 1: cast + transpose. in [R][C] fp32 -> out [C][R] bf16. 64x64 tiles.
// ---------------------------------------------------------------------------
__global__ __launch_bounds__(256) void transpose_cast_kernel(
    const float* __restrict__ in, unsigned short* __restrict__ outp, int R,
    int C) {
  __shared__ float tile[64][65];
  const int c0 = blockIdx.x * 64, r0 = blockIdx.y * 64;
  for (int i = threadIdx.x; i < 64 * 64; i += 256) {
    int r = i >> 6, c = i & 63;
    tile[r][c] = in[(size_t)(r0 + r) * C + c0 + c];
  }
  __syncthreads();
  for (int i = threadIdx.x; i < 64 * 64; i += 256) {
    int c = i >> 6, r = i & 63;
    outp[(size_t)(c0 + c) * R + r0 + r] = f2bf(tile[r][c]);
  }
}

// ---------------------------------------------------------------------------
// Kernel 1: QKV projection, bf16 MFMA (m97 structure, unchanged from r3).
// ---------------------------------------------------------------------------
__global__ __launch_bounds__(256) void gemm_qkv_mfma(
    const unsigned short* __restrict__ xb, const unsigned short* __restrict__ Wt,
    const float* __restrict__ bias, unsigned short* __restrict__ Qb,
    unsigned short* __restrict__ Kb, unsigned short* __restrict__ Vtb) {
  __shared__ unsigned short As[128 * 32];
  __shared__ unsigned short Bs[128 * 32];
  const int tid = threadIdx.x;
  const int w = tid >> 6, lane = tid & 63;
  const int quad = lane >> 4, l15 = lane & 15;
  const int wm = w >> 1, wn = w & 1;
  const int m0 = blockIdx.x * 128, n0 = blockIdx.y * 128;

  const unsigned short* ga = xb + (size_t)(m0 + (tid >> 2)) * 512 + (tid & 3) * 8;
  const unsigned short* gb = Wt + (size_t)(n0 + (tid >> 2)) * 512 + (tid & 3) * 8;
  unsigned short* lA = As + tid * 8;
  unsigned short* lB = Bs + tid * 8;

  f32x4 acc[4][4] = {};
  for (int k0 = 0; k0 < 512; k0 += 32) {
    async_lds16(ga + k0, lA);
    async_lds16(ga + 64 * 512 + k0, lA + 2048);
    async_lds16(gb + k0, lB);
    async_lds16(gb + 64 * 512 + k0, lB + 2048);
    __syncthreads();
    bf16x8 af[4], bfr[4];
#pragma unroll
    for (int mb = 0; mb < 4; ++mb)
      af[mb] = *(const bf16x8*)&As[(wm * 64 + mb * 16 + l15) * 32 + quad * 8];
#pragma unroll
    for (int nb = 0; nb < 4; ++nb)
      bfr[nb] = *(const bf16x8*)&Bs[(wn * 64 + nb * 16 + l15) * 32 + quad * 8];
#pragma unroll
    for (int mb = 0; mb < 4; ++mb)
#pragma unroll
      for (int nb = 0; nb < 4; ++nb)
        acc[mb][nb] = __builtin_amdgcn_mfma_f32_16x16x32_bf16(
            af[mb], bfr[nb], acc[mb][nb], 0, 0, 0);
    __syncthreads();
  }

  const int cbase = n0 + wn * 64;
  const int three = cbase >> 9;
  const int h = (cbase >> 6) & 7;
  const int bh = ((m0 >> 11) << 3) + h;
  const int t0 = (m0 & 2047) + wm * 64;
  float bv[4];
#pragma unroll
  for (int nb = 0; nb < 4; ++nb) bv[nb] = bias[cbase + nb * 16 + l15];

  if (three == 2) {
#pragma unroll
    for (int mb = 0; mb < 4; ++mb)
#pragma unroll
      for (int nb = 0; nb < 4; ++nb) {
        int trow = t0 + mb * 16 + quad * 4;
        ushort4 v = {f2bf(acc[mb][nb][0] + bv[nb]), f2bf(acc[mb][nb][1] + bv[nb]),
                     f2bf(acc[mb][nb][2] + bv[nb]), f2bf(acc[mb][nb][3] + bv[nb])};
        *(ushort4*)(Vtb + ((size_t)bh * HDIM + nb * 16 + l15) * SEQ_T + trow) = v;
      }
  } else {
    unsigned short* dst = three ? Kb : Qb;
    const float sc = three ? 1.0f : QSCALE;
#pragma unroll
    for (int mb = 0; mb < 4; ++mb)
#pragma unroll
      for (int nb = 0; nb < 4; ++nb)
#pragma unroll
        for (int r = 0; r < 4; ++r) {
          int trow = t0 + mb * 16 + quad * 4 + r;
          dst[((size_t)bh * SEQ_T + trow) * HDIM + nb * 16 + l15] =
              f2bf((acc[mb][nb][r] + bv[nb]) * sc);
        }
  }
}

// ---------------------------------------------------------------------------
// Kernel 2 (v2): causal flash attention, transposed-score formulation.
// S^T = K.Q^T (q = lane&15 -> per-lane softmax stats, 2 shuffles total).
// O^T = V^T.P^T; P^T goes C-layout -> wave-private LDS (conflict-free b64
// writes / b128 reads) -> B-fragments. Double-buffered K/V staging with
// global->reg prefetch, ONE barrier per tile. Load-balanced: block p does
// q-tiles p and 31-p (exactly 33 key-tiles each). Diagonal tiles: wave w
// computes only key-blocks nb <= w.
// ---------------------------------------------------------------------------
__global__ __launch_bounds__(256) void attn_mfma2(
    const unsigned short* __restrict__ Qb, const unsigned short* __restrict__ Kb,
    const unsigned short* __restrict__ Vtb, unsigned short* __restrict__ AOb) {
  __shared__ __align__(16) unsigned short Ks[2][64][72];
  __shared__ __align__(16) unsigned short Vs[2][64][72];
  __shared__ __align__(16) unsigned short Pt[4][16][72];
  const int tid = threadIdx.x;
  const int w = tid >> 6, lane = tid & 63;
  const int quad = lane >> 4, l15 = lane & 15;
  const int bh = blockIdx.y;
  const int p = blockIdx.x;
  const int qt0 = p, qt1 = 31 - p;
  const int nt0 = p + 1;           // tiles for phase 0
  const int TOT = 33;              // nt0 + (32 - p)

  const unsigned short* kbase = Kb + (size_t)bh * SEQ_T * HDIM;
  const unsigned short* vbase = Vtb + (size_t)bh * HDIM * SEQ_T;
  const int sr = tid >> 3, scol = (tid & 7) * 8;

  // phase-0 Q fragments (B-operand of S^T: same data as A-frag of Q)
  bf16x8 qf0, qf1;
  {
    const unsigned short* qp =
        Qb + ((size_t)bh * SEQ_T + qt0 * 64 + w * 16 + l15) * HDIM + quad * 8;
    qf0 = *(const bf16x8*)(qp);
    qf1 = *(const bf16x8*)(qp + 32);
  }
  f32x4 O[4] = {{0.f, 0.f, 0.f, 0.f}, {0.f, 0.f, 0.f, 0.f},
                {0.f, 0.f, 0.f, 0.f}, {0.f, 0.f, 0.f, 0.f}};
  float m_i = -INFINITY, l_i = 0.f;

  const int bb = bh >> 3, h = bh & 7;

  // stage tile 0 (phase 0, kt=0)
  uint4 rk0, rk1, rv0, rv1;
  {
    const unsigned short* kp = kbase + (size_t)sr * 64 + scol;
    rk0 = *(const uint4*)kp;
    rk1 = *(const uint4*)(kp + 32 * 64);
    const unsigned short* vp = vbase + (size_t)sr * SEQ_T + scol;
    rv0 = *(const uint4*)vp;
    rv1 = *(const uint4*)(vp + 32 * SEQ_T);
  }
  *(uint4*)&Ks[0][sr][scol] = rk0;
  *(uint4*)&Ks[0][sr + 32][scol] = rk1;
  *(uint4*)&Vs[0][sr][scol] = rv0;
  *(uint4*)&Vs[0][sr + 32][scol] = rv1;
  __syncthreads();

  for (int i = 0; i < TOT; ++i) {
    const int cur = i & 1;
    const int phase = (i >= nt0) ? 1 : 0;
    const int kt = i - (phase ? nt0 : 0);
    const int qt = phase ? qt1 : qt0;
    const bool diag = (kt == qt);

    // prefetch next tile global -> regs (latency overlaps compute below)
    if (i + 1 < TOT) {
      const int np = (i + 1 >= nt0) ? 1 : 0;
      const int nkt = (i + 1) - (np ? nt0 : 0);
      const unsigned short* kp = kbase + (size_t)(nkt * 64 + sr) * 64 + scol;
      rk0 = *(const uint4*)kp;
      rk1 = *(const uint4*)(kp + 32 * 64);
      const unsigned short* vp = vbase + (size_t)sr * SEQ_T + nkt * 64 + scol;
      rv0 = *(const uint4*)vp;
      rv1 = *(const uint4*)(vp + 32 * SEQ_T);
    }

    // ---- S^T = K.Q^T over this 64-key tile ----
    const int nb_lim = diag ? (w + 1) : 4;
    f32x4 S[4];
#pragma unroll
    for (int nb = 0; nb < 4; ++nb) {
      if (nb < nb_lim) {
        const unsigned short* kr = &Ks[cur][nb * 16 + l15][quad * 8];
        f32x4 z = {0.f, 0.f, 0.f, 0.f};
        z = __builtin_amdgcn_mfma_f32_16x16x32_bf16(*(const bf16x8*)(kr), qf0,
                                                    z, 0, 0, 0);
        S[nb] = __builtin_amdgcn_mfma_f32_16x16x32_bf16(
            *(const bf16x8*)(kr + 32), qf1, z, 0, 0, 0);
      }
    }
    if (diag) {
#pragma unroll
      for (int nb = 0; nb < 4; ++nb)
        if (nb < nb_lim) {
#pragma unroll
          for (int r = 0; r < 4; ++r) {
            int key = nb * 16 + quad * 4 + r;   // relative to tile base
            int q = w * 16 + l15;               // same base on diagonal
            if (key > q) S[nb][r] = -INFINITY;
          }
        }
    }

    // ---- online softmax, per-lane scalars (q = l15) ----
    float mx = -INFINITY;
#pragma unroll
    for (int nb = 0; nb < 4; ++nb)
      if (nb < nb_lim) {
#pragma unroll
        for (int r = 0; r < 4; ++r) mx = fmaxf(mx, S[nb][r]);
      }
    mx = fmaxf(mx, __shfl_xor(mx, 16));
    mx = fmaxf(mx, __shfl_xor(mx, 32));
    float mnew = fmaxf(m_i, mx);
    float alpha = exp2f(m_i - mnew);
    m_i = mnew;
    float rs = 0.f;
#pragma unroll
    for (int nb = 0; nb < 4; ++nb)
      if (nb < nb_lim) {
#pragma unroll
        for (int r = 0; r < 4; ++r) {
          float pp = exp2f(S[nb][r] - mnew);
          S[nb][r] = pp;
          rs += pp;
        }
      }
    rs += __shfl_xor(rs, 16);
    rs += __shfl_xor(rs, 32);
    l_i = l_i * alpha + rs;
#pragma unroll
    for (int nbd = 0; nbd < 4; ++nbd)
#pragma unroll
      for (int r = 0; r < 4; ++r) O[nbd][r] *= alpha;

    // ---- P^T -> wave-private LDS (b64 writes, conflict-free) ----
#pragma unroll
    for (int nb = 0; nb < 4; ++nb) {
      if (nb < nb_lim) {
        ushort4 pv = {f2bf(S[nb][0]), f2bf(S[nb][1]), f2bf(S[nb][2]),
                      f2bf(S[nb][3])};
        *(ushort4*)&Pt[w][l15][nb * 16 + quad * 4] = pv;
      } else if (diag) {
        ushort4 z4 = {0, 0, 0, 0};
        *(ushort4*)&Pt[w][l15][nb * 16 + quad * 4] = z4;
      }
    }

    // ---- O^T += V^T.P^T ----
    const int kpv = (!diag || w >= 2) ? 2 : 1;
    const unsigned short* pr = &Pt[w][l15][quad * 8];
    bf16x8 pb0 = *(const bf16x8*)(pr);
    bf16x8 pb1 = *(const bf16x8*)(pr + 32);
#pragma unroll
    for (int nbd = 0; nbd < 4; ++nbd) {
      const unsigned short* vr = &Vs[cur][nbd * 16 + l15][quad * 8];
      O[nbd] = __builtin_amdgcn_mfma_f32_16x16x32_bf16(*(const bf16x8*)(vr),
                                                       pb0, O[nbd], 0, 0, 0);
      if (kpv == 2)
        O[nbd] = __builtin_amdgcn_mfma_f32_16x16x32_bf16(
            *(const bf16x8*)(vr + 32), pb1, O[nbd], 0, 0, 0);
    }

    // ---- store prefetched tile into alternate buffer ----
    if (i + 1 < TOT) {
      const int nxt = cur ^ 1;
      *(uint4*)&Ks[nxt][sr][scol] = rk0;
      *(uint4*)&Ks[nxt][sr + 32][scol] = rk1;
      *(uint4*)&Vs[nxt][sr][scol] = rv0;
      *(uint4*)&Vs[nxt][sr + 32][scol] = rv1;
    }
    __syncthreads();

    // ---- phase boundary: write phase-0 output, reset, load phase-1 Q ----
    if (i == nt0 - 1) {
      float inv = 1.0f / l_i;
      int qrow = qt0 * 64 + w * 16 + l15;
      unsigned short* dst =
          AOb + ((size_t)bb * SEQ_T + qrow) * D_MODEL + (h << 6);
#pragma unroll
      for (int nbd = 0; nbd < 4; ++nbd) {
        ushort4 o4 = {f2bf(O[nbd][0] * inv), f2bf(O[nbd][1] * inv),
                      f2bf(O[nbd][2] * inv), f2bf(O[nbd][3] * inv)};
        *(ushort4*)(dst + nbd * 16 + quad * 4) = o4;
      }
      const unsigned short* qp =
          Qb + ((size_t)bh * SEQ_T + qt1 * 64 + w * 16 + l15) * HDIM + quad * 8;
      qf0 = *(const bf16x8*)(qp);
      qf1 = *(const bf16x8*)(qp + 32);
#pragma unroll
      for (int nbd = 0; nbd < 4; ++nbd) {
        O[nbd][0] = 0.f; O[nbd][1] = 0.f; O[nbd][2] = 0.f; O[nbd][3] = 0.f;
      }
      m_i = -INFINITY;
      l_i = 0.f;
    }
  }

  // phase-1 epilogue
  {
    float inv = 1.0f / l_i;
    int qrow = qt1 * 64 + w * 16 + l15;
    unsigned short* dst = AOb + ((size_t)bb * SEQ_T + qrow) * D_MODEL + (h << 6);
#pragma unroll
    for (int nbd = 0; nbd < 4; ++nbd) {
      ushort4 o4 = {f2bf(O[nbd][0] * inv), f2bf(O[nbd][1] * inv),
                    f2bf(O[nbd][2] * inv), f2bf(O[nbd][3] * inv)};
      *(ushort4*)(dst + nbd * 16 + quad * 4) = o4;
    }
  }
}

// ---------------------------------------------------------------------------
// Kernel 3: output projection, bf16 MFMA (unchanged from r3).
// ---------------------------------------------------------------------------
__global__ __launch_bounds__(256) void gemm_out_mfma(
    const unsigned short* __restrict__ AOb, const unsigned short* __restrict__ Wot,
    const float* __restrict__ bias, float* __restrict__ out) {
  __shared__ unsigned short As[128 * 32];
  __shared__ unsigned short Bs[128 * 32];
  const int tid = threadIdx.x;
  const int w = tid >> 6, lane = tid & 63;
  const int quad = lane >> 4, l15 = lane & 15;
  const int wm = w >> 1, wn = w & 1;
  const int m0 = blockIdx.x * 128, n0 = blockIdx.y * 128;

  const unsigned short* ga = AOb + (size_t)(m0 + (tid >> 2)) * 512 + (tid & 3) * 8;
  const unsigned short* gb = Wot + (size_t)(n0 + (tid >> 2)) * 512 + (tid & 3) * 8;
  unsigned short* lA = As + tid * 8;
  unsigned short* lB = Bs + tid * 8;

  f32x4 acc[4][4] = {};
  for (int k0 = 0; k0 < 512; k0 += 32) {
    async_lds16(ga + k0, lA);
    async_lds16(ga + 64 * 512 + k0, lA + 2048);
    async_lds16(gb + k0, lB);
    async_lds16(gb + 64 * 512 + k0, lB + 2048);
    __syncthreads();
    bf16x8 af[4], bfr[4];
#pragma unroll
    for (int mb = 0; mb < 4; ++mb)
      af[mb] = *(const bf16x8*)&As[(wm * 64 + mb * 16 + l15) * 32 + quad * 8];
#pragma unroll
    for (int nb = 0; nb < 4; ++nb)
      bfr[nb] = *(const bf16x8*)&Bs[(wn * 64 + nb * 16 + l15) * 32 + quad * 8];
#pragma unroll
    for (int mb = 0; mb < 4; ++mb)
#pragma unroll
      for (int nb = 0; nb < 4; ++nb)
        acc[mb][nb] = __builtin_amdgcn_mfma_f32_16x16x32_bf16(
            af[mb], bfr[nb], acc[mb][nb], 0, 0, 0);
    __syncthreads();
  }

  const int cbase = n0 + wn * 64;
  const int rbase = m0 + wm * 64;
  float bv[4];
#pragma unroll
  for (int nb = 0; nb < 4; ++nb) bv[nb] = bias[cbase + nb * 16 + l15];
#pragma unroll
  for (int mb = 0; mb < 4; ++mb)
#pragma unroll
    for (int nb = 0; nb < 4; ++nb)
#pragma unroll
      for (int r = 0; r < 4; ++r)
        out[(size_t)(rbase + mb * 16 + quad * 4 + r) * 512 + cbase + nb * 16 +
            l15] = acc[mb][nb][r] + bv[nb];
}

// ---------------------------------------------------------------------------
extern "C" void kernel_launch(void* const* d_in, const int* in_sizes, int n_in,
                              void* d_out, int out_size, void* d_ws,
                              size_t ws_size, hipStream_t stream) {
  const float* x     = (const float*)d_in[0];
  const float* W_qkv = (const float*)d_in[1];
  const float* b_qkv = (const float*)d_in[2];
  const float* W_out = (const float*)d_in[3];
  const float* b_out = (const float*)d_in[4];
  float* out = (float*)d_out;

  const size_t NX = (size_t)4 * SEQ_T * D_MODEL;        // 4,194,304
  unsigned short* xb   = (unsigned short*)d_ws;          // [8192][512]
  unsigned short* Wqkt = xb + NX;                        // [1536][512]
  unsigned short* Wot  = Wqkt + (size_t)1536 * 512;      // [512][512]
  unsigned short* Qb   = Wot + (size_t)512 * 512;        // [bh][t][64]
  unsigned short* Kb   = Qb + NX;
  unsigned short* Vtb  = Kb + NX;                        // [bh][dv][t]
  unsigned short* AOb  = Vtb + NX;                       // [8192][512]

  cast_bf16_kernel<<<NX / 2048, 256, 0, stream>>>(x, xb);
  transpose_cast_kernel<<<dim3(24, 8), 256, 0, stream>>>(W_qkv, Wqkt, 512, 1536);
  transpose_cast_kernel<<<dim3(8, 8), 256, 0, stream>>>(W_out, Wot, 512, 512);

  gemm_qkv_mfma<<<dim3(64, 12), 256, 0, stream>>>(xb, Wqkt, b_qkv, Qb, Kb, Vtb);
  attn_mfma2<<<dim3(16, 4 * NHEADS), 256, 0, stream>>>(Qb, Kb, Vtb, AOb);
  gemm_out_mfma<<<dim3(64, 4), 256, 0, stream>>>(AOb, Wot, b_out, out);
}